// Round 10
// baseline (340.377 us; speedup 1.0000x reference)
//
#include <hip/hip_runtime.h>
#include <hip/hip_bf16.h>

// Problem: B=64, S=1024, H=1024, A=512, E=512
// scores = tanh(encoded@W_enc + b_enc + states@W_dec + b_dec) . w_out (+b_out: softmax-invariant)
// weights = softmax(scores); attention = weights . encoded
// GRU: x=[inputs,attention]; gi=x@W_ih+b_ih; gh=states@W_hh+b_hh; gates -> h_new

typedef __attribute__((ext_vector_type(8))) __bf16 bf16x8;
typedef __attribute__((ext_vector_type(4))) __bf16 bf16x4;
typedef __attribute__((ext_vector_type(4))) float f32x4;

__device__ __forceinline__ float fast_tanh(float x) {
  float xa = fminf(fmaxf(x, -15.f), 15.f);
  float e = __expf(2.f * xa);
  return (e - 1.f) / (e + 1.f);
}

// global -> LDS direct DMA, 16B per lane. LDS dest = wave-uniform base + lane*16.
#define GLOAD16(G, L)                                                              \
  __builtin_amdgcn_global_load_lds(                                                \
      (const __attribute__((address_space(1))) unsigned int*)(const void*)(G),     \
      (__attribute__((address_space(3))) unsigned int*)(void*)(L), 16, 0, 0)

// ---------------- Kernel P: convert encoded f32 -> bf16 (streaming)
__global__ __launch_bounds__(256) void conv_kernel(const float* __restrict__ in,
                                                   __bf16* __restrict__ out, long n16) {
  long stride = (long)gridDim.x * 256;
  for (long i = (long)blockIdx.x * 256 + threadIdx.x; i < n16; i += stride) {
    const f32x4* p = (const f32x4*)(in + i * 16);
    f32x4 v0 = p[0], v1 = p[1], v2 = p[2], v3 = p[3];
    bf16x8 o0, o1;
#pragma unroll
    for (int j = 0; j < 4; ++j) {
      o0[j] = (__bf16)v0[j]; o0[4 + j] = (__bf16)v1[j];
      o1[j] = (__bf16)v2[j]; o1[4 + j] = (__bf16)v3[j];
    }
    *(bf16x8*)(out + i * 16) = o0;
    *(bf16x8*)(out + i * 16 + 8) = o1;
  }
}

// ---------------- Kernel T: transpose+convert W_enc [1024][512] f32 -> Wt [512][1024] bf16
__global__ __launch_bounds__(256) void wenc_t_kernel(const float* __restrict__ W,
                                                     __bf16* __restrict__ Wt) {
  __shared__ float tile[32][33];
  int k0 = blockIdx.x * 32, a0 = blockIdx.y * 32;
  int tid = threadIdx.x;
  int r = tid >> 3, c4 = (tid & 7) * 4;
  f32x4 v = *(const f32x4*)(W + (long)(k0 + r) * 512 + a0 + c4);
  tile[r][c4 + 0] = v.x; tile[r][c4 + 1] = v.y;
  tile[r][c4 + 2] = v.z; tile[r][c4 + 3] = v.w;
  __syncthreads();
  int a = tid >> 3, k4 = (tid & 7) * 4;
  bf16x4 o = { (__bf16)tile[k4 + 0][a], (__bf16)tile[k4 + 1][a],
               (__bf16)tile[k4 + 2][a], (__bf16)tile[k4 + 3][a] };
  *(bf16x4*)(Wt + (long)(a0 + a) * 1024 + k0 + k4) = o;
}

// ---------------- Kernel A: addv[b][a] = b_enc[a]+b_dec[a]+sum_h states[b,h]*W_dec[h,a]
__global__ __launch_bounds__(256) void dec_proj_kernel(
    const float* __restrict__ states, const float* __restrict__ W_dec,
    const float* __restrict__ b_enc, const float* __restrict__ b_dec,
    float* __restrict__ addv) {
  int b = blockIdx.x, tid = threadIdx.x;
  int a = blockIdx.y * 256 + tid;
  __shared__ float sl[1024];
  for (int i = tid; i < 1024; i += 256) sl[i] = states[b * 1024 + i];
  __syncthreads();
  float c0 = 0.f, c1 = 0.f, c2 = 0.f, c3 = 0.f;
#pragma unroll 4
  for (int i = 0; i < 256; ++i) {
    c0 += sl[i]         * W_dec[(i)        * 512 + a];
    c1 += sl[i + 256]   * W_dec[(i + 256)  * 512 + a];
    c2 += sl[i + 512]   * W_dec[(i + 512)  * 512 + a];
    c3 += sl[i + 768]   * W_dec[(i + 768)  * 512 + a];
  }
  addv[b * 512 + a] = c0 + c1 + c2 + c3 + b_enc[a] + b_dec[a];
}

// ---------------- Kernel B: 256x128 tile, BK=32, 512 thr / 8 waves (wave = 64x64).
// 3-buffer LDS (24KB each) = 74KB total -> 2 BLOCKS/CU (cross-block TLP restores m97's
// overlap mechanism). Depth-2 prefetch, counted vmcnt(3) (never 0 in loop), barrier ->
// STAGE(issue-early) -> COMPUTE order (R9-verified race-free). Involution source swizzle
// q^((row>>1)&3): 2-way LDS read aliasing = free.
// LDS: buf i @ i*24576 (A 16KB + B 8KB), red [256][2] @ 73728. 75776 B total.
__global__ __launch_bounds__(512, 4) void enc_score_kernel(
    const __bf16* __restrict__ encB,  // [65536][1024] bf16
    const __bf16* __restrict__ Wt,    // [512][1024] bf16 (W_enc^T)
    const float* __restrict__ addv,   // [64][512]
    const float* __restrict__ w_out,  // [512]
    float* __restrict__ psc)          // [4][65536]
{
  __shared__ __attribute__((aligned(16))) char smem[75776];
  float* red = (float*)(smem + 73728);  // [256][2]

  const int d = blockIdx.x;   // 1024
  const int xcd = d & 7;
  const int slot = d >> 3;    // 0..127
  const int bn = slot & 3;
  const int bm = ((slot >> 2) << 3) | xcd;  // 0..255; bn-siblings share bm AND xcd

  const int tid = threadIdx.x;
  const int lane = tid & 63;
  const int wid = tid >> 6;   // 0..7
  const int wr = wid >> 1;    // 0..3 (64 rows each)
  const int wc = wid & 1;     // 0..1 (64 cols each)
  const int lr = lane & 15;
  const int lkb = lane >> 4;  // 0..3

  const long row0 = (long)bm * 256;
  const int col0 = bn * 128;

  // staging: granule (row, q); A: row = tid>>2 (+128 for 2nd load), B: col = tid>>2; q = tid&3
  // source chunk = q ^ ((row>>1)&3)  (involution; +128 preserves bits 1-2)
  const int sk8 = (tid & 3) ^ ((tid >> 3) & 3);
  const __bf16* gA = encB + (row0 + (tid >> 2)) * 1024 + sk8 * 8;
  const __bf16* gB = Wt + (long)(col0 + (tid >> 2)) * 1024 + sk8 * 8;
  const int ldsW = wid * 1024;  // + lane*16 added by HW

  // fragment read: global chunk lkb lives at LDS slot lkb ^ ((row>>1)&3); (row>>1)&3 == (lr>>1)&3
  const int foff = (lkb ^ ((lr >> 1) & 3)) << 4;
  const int aRowB = (wr * 64 + lr) * 64;  // + m*1024 (16 rows)
  const int bColB = (wc * 64 + lr) * 64;  // + n*1024

  f32x4 acc[4][4];
#pragma unroll
  for (int m = 0; m < 4; ++m)
#pragma unroll
    for (int n = 0; n < 4; ++n) acc[m][n] = (f32x4){0.f, 0.f, 0.f, 0.f};

#define STAGE(SBUF, KT) do {                                                       \
    const __bf16* _a = gA + (KT) * 32;                                             \
    const __bf16* _b = gB + (KT) * 32;                                             \
    char* _base = smem + (SBUF) * 24576;                                           \
    GLOAD16(_a,          _base + ldsW);                                            \
    GLOAD16(_a + 131072, _base + 8192 + ldsW);                                     \
    GLOAD16(_b,          _base + 16384 + ldsW);                                    \
  } while (0)

#define COMPUTE(CBUF) do {                                                         \
    const char* _Ab = smem + (CBUF) * 24576;                                       \
    const char* _Bb = _Ab + 16384;                                                 \
    bf16x8 _af[4], _bv[4];                                                         \
    _Pragma("unroll") for (int _m = 0; _m < 4; ++_m)                               \
      _af[_m] = *(const bf16x8*)(_Ab + aRowB + _m * 1024 + foff);                  \
    _Pragma("unroll") for (int _n = 0; _n < 4; ++_n)                               \
      _bv[_n] = *(const bf16x8*)(_Bb + bColB + _n * 1024 + foff);                  \
    __builtin_amdgcn_s_setprio(1);                                                 \
    _Pragma("unroll") for (int _m = 0; _m < 4; ++_m)                               \
      _Pragma("unroll") for (int _n = 0; _n < 4; ++_n)                             \
        acc[_m][_n] =                                                              \
            __builtin_amdgcn_mfma_f32_16x16x32_bf16(_af[_m], _bv[_n], acc[_m][_n], 0, 0, 0); \
    __builtin_amdgcn_s_setprio(0);                                                 \
  } while (0)

#define WAITBAR(N) do {                                                            \
    asm volatile("s_waitcnt vmcnt(" #N ")" ::: "memory");                          \
    __builtin_amdgcn_sched_barrier(0);                                             \
    __builtin_amdgcn_s_barrier();                                                  \
    __builtin_amdgcn_sched_barrier(0);                                             \
  } while (0)

#define ITER(KT, CBUF, SBUF) do {                                                  \
    WAITBAR(3);                       /* tile KT complete across all waves */      \
    STAGE(SBUF, (KT) + 2);            /* issue-early; SBUF freed in iter KT-1 */   \
    __builtin_amdgcn_sched_barrier(0);                                             \
    COMPUTE(CBUF);                                                                 \
  } while (0)

  // prologue: tiles 0,1 in flight (6 outstanding loads/thread)
  STAGE(0, 0);
  STAGE(1, 1);

  for (int k3 = 0; k3 < 30; k3 += 3) {
    ITER(k3 + 0, 0, 2);
    ITER(k3 + 1, 1, 0);
    ITER(k3 + 2, 2, 1);
  }
  WAITBAR(3);
  COMPUTE(0);                         // kt=30
  WAITBAR(0);
  COMPUTE(1);                         // kt=31

#undef STAGE
#undef COMPUTE
#undef WAITBAR
#undef ITER

  // Epilogue: per-row sum of tanh(acc + addv[b][col]) * w_out[col]
  // C/D layout: col = lane&15, row = (lane>>4)*4 + reg
  const int b = bm >> 2;  // 256 rows/block, 1024/batch
  const float* addvb = addv + b * 512;
  float rowsum[4][4];
#pragma unroll
  for (int m = 0; m < 4; ++m)
#pragma unroll
    for (int reg = 0; reg < 4; ++reg) rowsum[m][reg] = 0.f;

#pragma unroll
  for (int m = 0; m < 4; ++m) {
#pragma unroll
    for (int n = 0; n < 4; ++n) {
      int col = col0 + wc * 64 + n * 16 + lr;
      float av = addvb[col];
      float wo = w_out[col];
#pragma unroll
      for (int reg = 0; reg < 4; ++reg)
        rowsum[m][reg] += fast_tanh(acc[m][n][reg] + av) * wo;
    }
  }
#pragma unroll
  for (int m = 0; m < 4; ++m)
#pragma unroll
    for (int reg = 0; reg < 4; ++reg) {
      float v = rowsum[m][reg];
      v += __shfl_xor(v, 1, 64);
      v += __shfl_xor(v, 2, 64);
      v += __shfl_xor(v, 4, 64);
      v += __shfl_xor(v, 8, 64);
      rowsum[m][reg] = v;
    }
  __syncthreads();
  if (lr == 0) {
#pragma unroll
    for (int m = 0; m < 4; ++m)
#pragma unroll
      for (int reg = 0; reg < 4; ++reg)
        red[(wr * 64 + m * 16 + lkb * 4 + reg) * 2 + wc] = rowsum[m][reg];
  }
  __syncthreads();
  if (tid < 256)
    psc[(long)bn * 65536 + row0 + tid] = red[tid * 2] + red[tid * 2 + 1];
}

// ---------------- Kernel C: softmax over S=1024 per batch (4 psc partials)
__global__ __launch_bounds__(256) void softmax_kernel(const float* __restrict__ psc,
                                                      float* __restrict__ wts) {
  int b = blockIdx.x, tid = threadIdx.x;
  __shared__ float sred[8];
  float sc[4];
  float mx = -1e30f;
#pragma unroll
  for (int i = 0; i < 4; ++i) {
    long r = (long)b * 1024 + tid + i * 256;
    sc[i] = psc[r] + psc[65536 + r] + psc[2 * 65536 + r] + psc[3 * 65536 + r];
    mx = fmaxf(mx, sc[i]);
  }
  for (int off = 1; off < 64; off <<= 1) mx = fmaxf(mx, __shfl_xor(mx, off, 64));
  if ((tid & 63) == 0) sred[tid >> 6] = mx;
  __syncthreads();
  mx = fmaxf(fmaxf(sred[0], sred[1]), fmaxf(sred[2], sred[3]));
  float e[4], sum = 0.f;
#pragma unroll
  for (int i = 0; i < 4; ++i) {
    e[i] = __expf(sc[i] - mx);
    sum += e[i];
  }
  for (int off = 1; off < 64; off <<= 1) sum += __shfl_xor(sum, off, 64);
  if ((tid & 63) == 0) sred[4 + (tid >> 6)] = sum;
  __syncthreads();
  sum = sred[4] + sred[5] + sred[6] + sred[7];
  float inv = 1.f / sum;
#pragma unroll
  for (int i = 0; i < 4; ++i) wts[(long)b * 1024 + tid + i * 256] = e[i] * inv;
}

// ---------------- Kernel D: attention partials from bf16 encB. 256 thr: split-s halves
// (serial depth 32) + LDS combine. 1024 blocks -> 16 waves/CU.
__global__ __launch_bounds__(256) void att_part_bf16_kernel(const __bf16* __restrict__ encB,
                                                            const float* __restrict__ wts,
                                                            float* __restrict__ attp) {
  int chunk = blockIdx.x;  // 16
  int b = blockIdx.y;      // 64
  int tid = threadIdx.x;
  int h8 = tid & 127;      // h octet
  int sh = tid >> 7;       // s parity 0/1
  __shared__ float sacc[1024];
  const __bf16* base = encB + ((long)b * 1024 + chunk * 64 + sh) * 1024 + h8 * 8;
  const float* w = wts + b * 1024 + chunk * 64 + sh;
  float a0[8], a1[8];
#pragma unroll
  for (int j = 0; j < 8; ++j) { a0[j] = 0.f; a1[j] = 0.f; }
#pragma unroll 4
  for (int s = 0; s < 64; s += 4) {
    bf16x8 v0 = *(const bf16x8*)(base + (long)s * 1024);
    bf16x8 v1 = *(const bf16x8*)(base + (long)(s + 2) * 1024);
    float w0 = w[s], w1 = w[s + 2];
#pragma unroll
    for (int j = 0; j < 8; ++j) {
      a0[j] += (float)v0[j] * w0;
      a1[j] += (float)v1[j] * w1;
    }
  }
  if (sh) {
#pragma unroll
    for (int j = 0; j < 8; ++j) sacc[h8 * 8 + j] = a0[j] + a1[j];
  }
  __syncthreads();
  if (!sh) {
    float* o = attp + ((long)(b * 16 + chunk)) * 1024 + h8 * 8;
#pragma unroll
    for (int j = 0; j < 8; ++j) o[j] = a0[j] + a1[j] + sacc[h8 * 8 + j];
  }
}

// ---------------- Kernel E: xcat[b][0:512]=inputs, xcat[b][512:1536]=sum_chunk attp
__global__ __launch_bounds__(256) void xcat_kernel(const float* __restrict__ inputs,
                                                   const float* __restrict__ attp,
                                                   float* __restrict__ xcat) {
  int b = blockIdx.y;
  int k = blockIdx.x * 256 + threadIdx.x;  // 0..1535
  float v;
  if (k < 512) {
    v = inputs[b * 512 + k];
  } else {
    int h = k - 512;
    v = 0.f;
#pragma unroll
    for (int c = 0; c < 16; ++c) v += attp[((long)(b * 16 + c)) * 1024 + h];
  }
  xcat[(long)b * 1536 + k] = v;
}

// ---------------- Kernel F: GRU GEMVs, batch-grouped: chunk-group pinned to one XCD
__global__ __launch_bounds__(512) void gru_gemv_kernel(
    const float* __restrict__ xcat, const float* __restrict__ states,
    const float* __restrict__ W_ih, const float* __restrict__ b_ih,
    const float* __restrict__ W_hh, const float* __restrict__ b_hh,
    float* __restrict__ gi, float* __restrict__ gh) {
  __shared__ float sx[12288];
  const int dd = blockIdx.x;            // 192
  const int xcd = dd & 7;
  const int n = dd >> 3;
  const int cgrp = xcd + 8 * (n >> 3);
  const int bg = n & 7;
  const int tid = threadIdx.x;
  const int lcol = tid & 255;
  const int bsel = (tid >> 8) * 4;

  if (cgrp < 12) {
    const int col = cgrp * 256 + lcol;
    const float* xb = xcat + (long)bg * 8 * 1536;
    for (int i = tid; i < 3072; i += 512) ((f32x4*)sx)[i] = ((const f32x4*)xb)[i];
    __syncthreads();
    float a0 = b_ih[col], a1 = a0, a2 = a0, a3 = a0;
    const float* x0 = sx + (bsel + 0) * 1536;
    const float* x1 = sx + (bsel + 1) * 1536;
    const float* x2 = sx + (bsel + 2) * 1536;
    const float* x3 = sx + (bsel + 3) * 1536;
    for (int k = 0; k < 1536; k += 4) {
      f32x4 v0 = *(const f32x4*)(x0 + k);
      f32x4 v1 = *(const f32x4*)(x1 + k);
      f32x4 v2 = *(const f32x4*)(x2 + k);
      f32x4 v3 = *(const f32x4*)(x3 + k);
#pragma unroll
      for (int j = 0; j < 4; ++j) {
        float w = W_ih[(long)(k + j) * 3072 + col];
        a0 += v0[j] * w; a1 += v1[j] * w; a2 += v2[j] * w; a3 += v3[j] * w;
      }
    }
    long o = (long)(bg * 8 + bsel) * 3072 + col;
    gi[o] = a0; gi[o + 3072] = a1; gi[o + 6144] = a2; gi[o + 9216] = a3;
  } else {
    const int col = (cgrp - 12) * 256 + lcol;
    const float* sb = states + (long)bg * 8 * 1024;
    for (int i = tid; i < 2048; i += 512) ((f32x4*)sx)[i] = ((const f32x4*)sb)[i];
    __syncthreads();
    float a0 = b_hh[col], a1 = a0, a2 = a0, a3 = a0;
    const float* x0 = sx + (bsel + 0) * 1024;
    const float* x1 = sx + (bsel + 1) * 1024;
    const float* x2 = sx + (bsel + 2) * 1024;
    const float* x3 = sx + (bsel + 3) * 1024;
    for (int k = 0; k < 1024; k += 4) {
      f32x4 v0 = *(const f32x4*)(x0 + k);
      f32x4 v1 = *(const f32x4*)(x1 + k);
      f32x4 v2 = *(const f32x4*)(x2 + k);
      f32x4 v3 = *(const f32x4*)(x3 + k);
#pragma unroll
      for (int j = 0; j < 4; ++j) {
        float w = W_hh[(long)(k + j) * 3072 + col];
        a0 += v0[j] * w; a1 += v1[j] * w; a2 += v2[j] * w; a3 += v3[j] * w;
      }
    }
    long o = (long)(bg * 8 + bsel) * 3072 + col;
    gh[o] = a0; gh[o + 3072] = a1; gh[o + 6144] = a2; gh[o + 9216] = a3;
  }
}

// ---------------- Kernel G: gates
__global__ __launch_bounds__(256) void gate_kernel(const float* __restrict__ gi,
                                                   const float* __restrict__ gh,
                                                   const float* __restrict__ states,
                                                   float* __restrict__ out) {
  int b = blockIdx.y;
  int j = blockIdx.x * 256 + threadIdx.x;
  long o = (long)b * 3072;
  float ir = gi[o + j], hr = gh[o + j];
  float iz = gi[o + 1024 + j], hz = gh[o + 1024 + j];
  float in_ = gi[o + 2048 + j], hn = gh[o + 2048 + j];
  float r = 1.f / (1.f + __expf(-(ir + hr)));
  float z = 1.f / (1.f + __expf(-(iz + hz)));
  float n = fast_tanh(in_ + r * hn);
  out[(long)b * 1024 + j] = (1.f - z) * n + z * states[(long)b * 1024 + j];
}

extern "C" void kernel_launch(void* const* d_in, const int* in_sizes, int n_in,
                              void* d_out, int out_size, void* d_ws, size_t ws_size,
                              hipStream_t stream) {
  const float* inputs  = (const float*)d_in[0];
  const float* states  = (const float*)d_in[1];
  const float* encoded = (const float*)d_in[2];
  const float* W_enc   = (const float*)d_in[3];
  const float* b_enc   = (const float*)d_in[4];
  const float* W_dec   = (const float*)d_in[5];
  const float* b_dec   = (const float*)d_in[6];
  const float* w_out   = (const float*)d_in[7];
  // d_in[8] = b_out: softmax-invariant, unused
  const float* W_ih    = (const float*)d_in[9];
  const float* b_ih    = (const float*)d_in[10];
  const float* W_hh    = (const float*)d_in[11];
  const float* b_hh    = (const float*)d_in[12];
  float* out = (float*)d_out;
  float* ws = (float*)d_ws;

  const long ENC_ELEMS = 64L * 1024 * 1024;   // encoded fp32 elements
  const long ENCB_FLOATS = ENC_ELEMS / 2;     // bf16 copy, in float slots

  __bf16* encB = (__bf16*)ws;
  float* base = ws + ENCB_FLOATS;

  float* addv = base;                 // 32768
  float* psc  = base + 32768;         // 4*65536 = 262144
  float* wts  = base + 294912;        // 65536
  float* attp = base + 360448;        // 64*16*1024 = 1048576
  float* xcat = base + 1409024;       // 98304
  float* gi   = base + 1507328;       // 196608
  float* gh   = base + 1703936;       // 196608
  __bf16* Wt  = (__bf16*)(base + 1900544);  // 512*1024 bf16

  conv_kernel<<<4096, 256, 0, stream>>>(encoded, encB, ENC_ELEMS / 16);

  wenc_t_kernel<<<dim3(32, 16), 256, 0, stream>>>(W_enc, Wt);

  dim3 gA(64, 2);
  dec_proj_kernel<<<gA, 256, 0, stream>>>(states, W_dec, b_enc, b_dec, addv);

  enc_score_kernel<<<1024, 512, 0, stream>>>(encB, Wt, addv, w_out, psc);

  softmax_kernel<<<64, 256, 0, stream>>>(psc, wts);

  dim3 gD(16, 64);
  att_part_bf16_kernel<<<gD, 256, 0, stream>>>(encB, wts, attp);

  dim3 gE(6, 64);
  xcat_kernel<<<gE, 256, 0, stream>>>(inputs, attp, xcat);

  gru_gemv_kernel<<<192, 512, 0, stream>>>(xcat, states, W_ih, b_ih, W_hh, b_hh, gi, gh);

  dim3 gG(4, 64);
  gate_kernel<<<gG, 256, 0, stream>>>(gi, gh, states, out);
}